// Round 5
// baseline (839.556 us; speedup 1.0000x reference)
//
#include <hip/hip_runtime.h>

// ScaledDotProductAttention: B=4 H=12 S=2048 DK=64, fp32 in/out.
// d_out = context [B,H,S,DK] then attn [B,H,S,S], concatenated.
//
// Pipeline: conv_k (K->bf16), trans_v (V->V^T bf16 padded), stats (softmax
// row max + 1/sum), main (QK^T -> normalize -> attn stores -> PV -> ctx).
// Main kernel uses LDS-only barriers (s_waitcnt lgkmcnt(0) + s_barrier) so
// global stores are NEVER drained inside the kernel - they overlap compute.

#define S_LEN 2048
#define D_K   64
#define NBH   48
#define VT_STRIDE 2080   // padded V^T row (breaks 4KB channel camping)

typedef __attribute__((ext_vector_type(8))) short short8v;   // 8 x bf16 (4 VGPR)
typedef __attribute__((ext_vector_type(4))) float float4v;

__device__ inline unsigned short f2bf(float f) {
    union { float f; unsigned u; } c; c.f = f;
    unsigned u = c.u;
    return (unsigned short)((u + 0x7FFFu + ((u >> 16) & 1u)) >> 16);  // RNE
}

// LDS-visibility barrier WITHOUT vmcnt drain: global stores stay in flight.
__device__ inline void wg_sync_lds() {
    asm volatile("s_waitcnt lgkmcnt(0)" ::: "memory");
    __builtin_amdgcn_s_barrier();
    __builtin_amdgcn_sched_barrier(0);
}

#define CEXP 0.18033688011112042f   // (1/sqrt(64)) * log2(e)

// ---------------- prepass: K f32 -> bf16 (same layout) ----------------
__global__ __launch_bounds__(256)
void conv_k_kernel(const float* __restrict__ K, unsigned short* __restrict__ Kbf) {
    const size_t N = (size_t)NBH * S_LEN * D_K;
    for (size_t i = ((size_t)blockIdx.x * 256 + threadIdx.x) * 4; i < N;
         i += (size_t)gridDim.x * 256 * 4) {
        float4v v = *reinterpret_cast<const float4v*>(K + i);
        unsigned p0 = (unsigned)f2bf(v[0]) | ((unsigned)f2bf(v[1]) << 16);
        unsigned p1 = (unsigned)f2bf(v[2]) | ((unsigned)f2bf(v[3]) << 16);
        uint2 pk; pk.x = p0; pk.y = p1;
        *reinterpret_cast<uint2*>(Kbf + i) = pk;
    }
}

// ---------------- prepass: V [bh][k][d] f32 -> VT [bh][d][k_pad] bf16 ----------------
__global__ __launch_bounds__(256)
void trans_v_kernel(const float* __restrict__ V, unsigned short* __restrict__ VT) {
    const int bh = blockIdx.y;
    const int k0 = blockIdx.x * 64;
    __shared__ unsigned short tile[64][66];
    const int t = threadIdx.x;
    {
        const int kr = t >> 2, dq = t & 3;
        const float* src = V + (size_t)bh * S_LEN * D_K + (size_t)(k0 + kr) * D_K + dq * 16;
        #pragma unroll
        for (int i = 0; i < 4; ++i) {
            float4v v = *reinterpret_cast<const float4v*>(src + i * 4);
            #pragma unroll
            for (int j = 0; j < 4; ++j) tile[kr][dq * 16 + i * 4 + j] = f2bf(v[j]);
        }
    }
    __syncthreads();
    {
        const int d = t >> 2, kq = t & 3;
        unsigned pk[8];
        #pragma unroll
        for (int i = 0; i < 8; ++i) {
            unsigned lo = tile[kq * 16 + 2 * i][d];
            unsigned hi = tile[kq * 16 + 2 * i + 1][d];
            pk[i] = lo | (hi << 16);
        }
        unsigned* dst = reinterpret_cast<unsigned*>(
            VT + (size_t)bh * D_K * VT_STRIDE + (size_t)d * VT_STRIDE + k0 + kq * 16);
        uint4 a; a.x = pk[0]; a.y = pk[1]; a.z = pk[2]; a.w = pk[3];
        uint4 b; b.x = pk[4]; b.y = pk[5]; b.z = pk[6]; b.w = pk[7];
        reinterpret_cast<uint4*>(dst)[0] = a;
        reinterpret_cast<uint4*>(dst)[1] = b;
    }
}

// ---------------- stats: per q-row softmax max + 1/sum (online) ----------------
// Grid (128, 48), 256 threads (4 waves). Wave w: keys [w*512, w*512+512).
__global__ __launch_bounds__(256)
void stats_kernel(const float* __restrict__ Qp, const unsigned short* __restrict__ Kbf,
                  float2* __restrict__ stats) {
    const int qt   = blockIdx.x;
    const int bh   = blockIdx.y;
    const int tid  = threadIdx.x;
    const int w    = tid >> 6;
    const int lane = tid & 63;
    const int lq   = lane & 15;
    const int lg   = lane >> 4;
    const int qg   = qt * 16;
    const size_t base = (size_t)bh * S_LEN * D_K;

    // Q fragment: identical code to main kernel -> bit-identical scores
    short8v q0, q1;
    {
        const float* qr = Qp + base + (size_t)(qg + lq) * D_K + lg * 8;
        float4v qa = *reinterpret_cast<const float4v*>(qr);
        float4v qb = *reinterpret_cast<const float4v*>(qr + 4);
        float4v qc = *reinterpret_cast<const float4v*>(qr + 32);
        float4v qd = *reinterpret_cast<const float4v*>(qr + 36);
        #pragma unroll
        for (int j = 0; j < 4; ++j) {
            q0[j]     = (short)f2bf(qa[j]);
            q0[4 + j] = (short)f2bf(qb[j]);
            q1[j]     = (short)f2bf(qc[j]);
            q1[4 + j] = (short)f2bf(qd[j]);
        }
    }

    const int kw = w * 512;
    float m = -3.0e38f, s = 0.f;
    #pragma unroll 4
    for (int kt = 0; kt < 32; ++kt) {
        const unsigned short* kr = Kbf + base + (size_t)(kw + kt * 16 + lq) * D_K + lg * 8;
        short8v k0 = *reinterpret_cast<const short8v*>(kr);
        short8v k1 = *reinterpret_cast<const short8v*>(kr + 32);
        float4v a = (float4v)0.0f;
        a = __builtin_amdgcn_mfma_f32_16x16x32_bf16(k0, q0, a, 0, 0, 0);
        a = __builtin_amdgcn_mfma_f32_16x16x32_bf16(k1, q1, a, 0, 0, 0);
        float m4 = fmaxf(fmaxf(a[0], a[1]), fmaxf(a[2], a[3]));
        float mn = fmaxf(m, m4);
        s = s * exp2f((m - mn) * CEXP);
        s += exp2f((a[0] - mn) * CEXP) + exp2f((a[1] - mn) * CEXP)
           + exp2f((a[2] - mn) * CEXP) + exp2f((a[3] - mn) * CEXP);
        m = mn;
    }
    // merge across the 4 lane-groups holding the same q-row
    #pragma unroll
    for (int off = 16; off < 64; off <<= 1) {
        float mo = __shfl_xor(m, off, 64);
        float so = __shfl_xor(s, off, 64);
        float mn = fmaxf(m, mo);
        s = s * exp2f((m - mn) * CEXP) + so * exp2f((mo - mn) * CEXP);
        m = mn;
    }
    __shared__ float sm[16][4], ss[16][4];
    if (lane < 16) { sm[lane][w] = m; ss[lane][w] = s; }
    __syncthreads();
    if (w == 0 && lane < 16) {
        float M = sm[lane][0], S = ss[lane][0];
        #pragma unroll
        for (int ww = 1; ww < 4; ++ww) {
            float mo = sm[lane][ww], so = ss[lane][ww];
            float mn = fmaxf(M, mo);
            S = S * exp2f((M - mn) * CEXP) + so * exp2f((mo - mn) * CEXP);
            M = mn;
        }
        float2 st; st.x = M; st.y = 1.0f / S;
        stats[(size_t)bh * S_LEN + qg + lane] = st;
    }
}

// ---------------- main fused kernel ----------------
// WG = 16 q rows x all 2048 keys. 8 waves; wave w owns keys [w*256, w*256+256).
// Swapped QK^T: lane holds P[q=lq][k = kt*16 + lg*4 + r].
__global__ __launch_bounds__(512)
void sdpa_main_kernel(const float* __restrict__ Qp,
                      const unsigned short* __restrict__ Kbf,
                      const unsigned short* __restrict__ VT,
                      const float2* __restrict__ stats,
                      float* __restrict__ ctx, float* __restrict__ attn) {
    const int qt   = blockIdx.x;
    const int bh   = blockIdx.y;
    const int tid  = threadIdx.x;
    const int w    = tid >> 6;
    const int lane = tid & 63;
    const int lq   = lane & 15;
    const int lg   = lane >> 4;
    const int qg   = qt * 16;
    const int kw   = w * 256;
    const size_t base = (size_t)bh * S_LEN * D_K;

    // One union region: abuf [4][2056] f32 (epilogue) / pbuf (PV) / ctxp (reduce)
    __shared__ __align__(16) char smem_raw[8 * 16 * 136 * 2];  // 34816 B
    auto pbuf = reinterpret_cast<unsigned short(*)[16][136]>(smem_raw);
    auto ctxp = reinterpret_cast<float(*)[16][64]>(smem_raw);
    float* abuf = reinterpret_cast<float*>(smem_raw);

    // stats (issue early; tiny broadcast load)
    const float2 st = stats[(size_t)bh * S_LEN + qg + lq];
    const float gm = st.x, rs = st.y;

    // ---- Q fragment
    short8v q0, q1;
    {
        const float* qr = Qp + base + (size_t)(qg + lq) * D_K + lg * 8;
        float4v qa = *reinterpret_cast<const float4v*>(qr);
        float4v qb = *reinterpret_cast<const float4v*>(qr + 4);
        float4v qc = *reinterpret_cast<const float4v*>(qr + 32);
        float4v qd = *reinterpret_cast<const float4v*>(qr + 36);
        #pragma unroll
        for (int j = 0; j < 4; ++j) {
            q0[j]     = (short)f2bf(qa[j]);
            q0[4 + j] = (short)f2bf(qb[j]);
            q1[j]     = (short)f2bf(qc[j]);
            q1[4 + j] = (short)f2bf(qd[j]);
        }
    }

    // ---- QK^T: 16 key-tiles of 16 per wave (no barriers anywhere here)
    float4v acc[16];
    #pragma unroll
    for (int kt = 0; kt < 16; ++kt) acc[kt] = (float4v)0.0f;
    #pragma unroll
    for (int kt = 0; kt < 16; ++kt) {
        const unsigned short* kr = Kbf + base + (size_t)(kw + kt * 16 + lq) * D_K + lg * 8;
        short8v k0 = *reinterpret_cast<const short8v*>(kr);
        short8v k1 = *reinterpret_cast<const short8v*>(kr + 32);
        acc[kt] = __builtin_amdgcn_mfma_f32_16x16x32_bf16(k0, q0, acc[kt], 0, 0, 0);
        acc[kt] = __builtin_amdgcn_mfma_f32_16x16x32_bf16(k1, q1, acc[kt], 0, 0, 0);
    }

    // ---- normalize with precomputed stats: attn values final in regs
    #pragma unroll
    for (int kt = 0; kt < 16; ++kt)
        #pragma unroll
        for (int r = 0; r < 4; ++r)
            acc[kt][r] = exp2f((acc[kt][r] - gm) * CEXP) * rs;

    // ---- attn epilogue FIRST: stores issue early, PV compute covers drain.
    // 4 chunks of 4 rows; every global store is 1KB contiguous per wave.
    float* attnb = attn + (size_t)bh * S_LEN * S_LEN + (size_t)qg * S_LEN;
    const int arow  = w >> 1;
    const int ahalf = w & 1;
    #pragma unroll
    for (int c = 0; c < 4; ++c) {
        if ((lq >> 2) == c) {                 // 16 lanes/wave hold rows c*4..c*4+3
            float* dst = abuf + (lq & 3) * 2056 + kw + lg * 4;
            #pragma unroll
            for (int kt = 0; kt < 16; ++kt)
                *reinterpret_cast<float4v*>(dst + kt * 16) = acc[kt];
        }
        wg_sync_lds();
        {
            const float* src = abuf + arow * 2056 + ahalf * 1024 + lane * 4;
            float* gdst = attnb + (size_t)(c * 4 + arow) * S_LEN + ahalf * 1024 + lane * 4;
            #pragma unroll
            for (int k = 0; k < 4; ++k) {
                float4v v = *reinterpret_cast<const float4v*>(src + k * 256);
                *reinterpret_cast<float4v*>(gdst + k * 256) = v;
            }
        }
        wg_sync_lds();   // abuf reuse safety (loads only; stores keep flying)
    }

    // ---- PV: two halves of 128 keys (pbuf wave-private, no barriers)
    float4v cacc[4];
    #pragma unroll
    for (int dt = 0; dt < 4; ++dt) cacc[dt] = (float4v)0.0f;

    #pragma unroll
    for (int half = 0; half < 2; ++half) {
        #pragma unroll
        for (int kth = 0; kth < 8; ++kth) {
            const int kt = half * 8 + kth;
            unsigned p01 = (unsigned)f2bf(acc[kt][0]) | ((unsigned)f2bf(acc[kt][1]) << 16);
            unsigned p23 = (unsigned)f2bf(acc[kt][2]) | ((unsigned)f2bf(acc[kt][3]) << 16);
            unsigned* dst = reinterpret_cast<unsigned*>(&pbuf[w][lq][kth * 16 + lg * 4]);
            dst[0] = p01;
            dst[1] = p23;
        }
        #pragma unroll
        for (int s2 = 0; s2 < 4; ++s2) {
            short8v pa = *reinterpret_cast<const short8v*>(&pbuf[w][lq][s2 * 32 + lg * 8]);
            const int kk = kw + half * 128 + s2 * 32 + lg * 8;
            #pragma unroll
            for (int dt = 0; dt < 4; ++dt) {
                short8v bv = *reinterpret_cast<const short8v*>(
                    VT + (size_t)bh * D_K * VT_STRIDE + (size_t)(dt * 16 + lq) * VT_STRIDE + kk);
                cacc[dt] = __builtin_amdgcn_mfma_f32_16x16x32_bf16(pa, bv, cacc[dt], 0, 0, 0);
            }
        }
    }

    // ---- cross-wave ctx reduce (ctxp aliases pbuf: LDS barrier first)
    wg_sync_lds();
    #pragma unroll
    for (int dt = 0; dt < 4; ++dt)
        #pragma unroll
        for (int r = 0; r < 4; ++r)
            ctxp[w][lg * 4 + r][dt * 16 + lq] = cacc[dt][r];
    wg_sync_lds();

    float* ctxb = ctx + base;
    for (int idx = tid; idx < 16 * 64; idx += 512) {
        const int q = idx >> 6, d = idx & 63;
        float sum = 0.f;
        #pragma unroll
        for (int ww = 0; ww < 8; ++ww) sum += ctxp[ww][q][d];
        ctxb[(size_t)(qg + q) * D_K + d] = sum;
    }
}

// ---------------- fallback (no workspace): R3-style self-contained ----------------
__global__ __launch_bounds__(512)
void sdpa_fallback_kernel(const float* __restrict__ Qp, const float* __restrict__ Kp,
                          const float* __restrict__ Vp,
                          float* __restrict__ ctx, float* __restrict__ attn) {
    const int qt = blockIdx.x, bh = blockIdx.y, tid = threadIdx.x;
    const int w = tid >> 6, lane = tid & 63, lq = lane & 15, lg = lane >> 4;
    const int qg = qt * 16, kw = w * 256;
    const size_t base = (size_t)bh * S_LEN * D_K;
    __shared__ __align__(16) char smem_raw[8 * 16 * 136 * 2];
    __shared__ float red_m[16][8], red_s[16][8];
    auto pbuf = reinterpret_cast<unsigned short(*)[16][136]>(smem_raw);
    auto ctxp = reinterpret_cast<float(*)[16][64]>(smem_raw);

    short8v q0, q1;
    {
        const float* qr = Qp + base + (size_t)(qg + lq) * D_K + lg * 8;
        #pragma unroll
        for (int j = 0; j < 8; ++j) {
            q0[j] = (short)f2bf(qr[j]);
            q1[j] = (short)f2bf(qr[32 + j]);
        }
    }
    float4v acc[16];
    #pragma unroll
    for (int kt = 0; kt < 16; ++kt) acc[kt] = (float4v)0.0f;
    #pragma unroll
    for (int kt = 0; kt < 16; ++kt) {
        const float* kr = Kp + base + (size_t)(kw + kt * 16 + lq) * D_K + lg * 8;
        short8v k0, k1;
        #pragma unroll
        for (int j = 0; j < 8; ++j) { k0[j] = (short)f2bf(kr[j]); k1[j] = (short)f2bf(kr[32 + j]); }
        acc[kt] = __builtin_amdgcn_mfma_f32_16x16x32_bf16(k0, q0, acc[kt], 0, 0, 0);
        acc[kt] = __builtin_amdgcn_mfma_f32_16x16x32_bf16(k1, q1, acc[kt], 0, 0, 0);
    }
    float m = -1e30f;
    #pragma unroll
    for (int kt = 0; kt < 16; ++kt)
        #pragma unroll
        for (int r = 0; r < 4; ++r) m = fmaxf(m, acc[kt][r]);
    m = fmaxf(m, __shfl_xor(m, 16, 64));
    m = fmaxf(m, __shfl_xor(m, 32, 64));
    if (lane < 16) red_m[lane][w] = m;
    __syncthreads();
    float gm = red_m[lq][0];
    #pragma unroll
    for (int ww = 1; ww < 8; ++ww) gm = fmaxf(gm, red_m[lq][ww]);
    float s = 0.f;
    #pragma unroll
    for (int kt = 0; kt < 16; ++kt)
        #pragma unroll
        for (int r = 0; r < 4; ++r) {
            float p = exp2f((acc[kt][r] - gm) * CEXP);
            acc[kt][r] = p; s += p;
        }
    s += __shfl_xor(s, 16, 64);
    s += __shfl_xor(s, 32, 64);
    if (lane < 16) red_s[lane][w] = s;
    __syncthreads();
    float gs = red_s[lq][0];
    #pragma unroll
    for (int ww = 1; ww < 8; ++ww) gs += red_s[lq][ww];
    const float rsv = 1.0f / gs;
    #pragma unroll
    for (int kt = 0; kt < 16; ++kt) acc[kt] = acc[kt] * rsv;

    float4v cacc[4];
    #pragma unroll
    for (int dt = 0; dt < 4; ++dt) cacc[dt] = (float4v)0.0f;
    #pragma unroll
    for (int half = 0; half < 2; ++half) {
        #pragma unroll
        for (int kth = 0; kth < 8; ++kth) {
            const int kt = half * 8 + kth;
            unsigned p01 = (unsigned)f2bf(acc[kt][0]) | ((unsigned)f2bf(acc[kt][1]) << 16);
            unsigned p23 = (unsigned)f2bf(acc[kt][2]) | ((unsigned)f2bf(acc[kt][3]) << 16);
            unsigned* dst = reinterpret_cast<unsigned*>(&pbuf[w][lq][kth * 16 + lg * 4]);
            dst[0] = p01; dst[1] = p23;
        }
        #pragma unroll
        for (int s2 = 0; s2 < 4; ++s2) {
            short8v pa = *reinterpret_cast<const short8v*>(&pbuf[w][lq][s2 * 32 + lg * 8]);
            const int kk = kw + half * 128 + s2 * 32 + lg * 8;
            #pragma unroll
            for (int dt = 0; dt < 4; ++dt) {
                short8v bv;
                #pragma unroll
                for (int j = 0; j < 8; ++j)
                    bv[j] = (short)f2bf(Vp[base + (size_t)(kk + j) * D_K + dt * 16 + lq]);
                cacc[dt] = __builtin_amdgcn_mfma_f32_16x16x32_bf16(pa, bv, cacc[dt], 0, 0, 0);
            }
        }
    }
    __syncthreads();
    #pragma unroll
    for (int dt = 0; dt < 4; ++dt)
        #pragma unroll
        for (int r = 0; r < 4; ++r)
            ctxp[w][lg * 4 + r][dt * 16 + lq] = cacc[dt][r];
    __syncthreads();
    float* ctxb = ctx + base;
    for (int idx = tid; idx < 16 * 64; idx += 512) {
        const int q = idx >> 6, d = idx & 63;
        float sum = 0.f;
        #pragma unroll
        for (int ww = 0; ww < 8; ++ww) sum += ctxp[ww][q][d];
        ctxb[(size_t)(qg + q) * D_K + d] = sum;
    }
    float* attnb = attn + (size_t)bh * S_LEN * S_LEN + (size_t)(qg + lq) * S_LEN + kw + lg * 4;
    #pragma unroll
    for (int kt = 0; kt < 16; ++kt)
        *reinterpret_cast<float4v*>(attnb + kt * 16) = acc[kt];
}

extern "C" void kernel_launch(void* const* d_in, const int* in_sizes, int n_in,
                              void* d_out, int out_size, void* d_ws, size_t ws_size,
                              hipStream_t stream) {
    const float* Q = (const float*)d_in[0];
    const float* K = (const float*)d_in[1];
    const float* V = (const float*)d_in[2];
    float* ctx  = (float*)d_out;
    float* attn = ctx + (size_t)NBH * S_LEN * D_K;

    const size_t nel  = (size_t)NBH * S_LEN * D_K;       // 6,291,456
    const size_t nvt  = (size_t)NBH * D_K * VT_STRIDE;   // padded VT elems
    const size_t nst  = (size_t)NBH * S_LEN;             // stats rows
    const size_t need = (nel + nvt) * 2 + nst * 8;
    dim3 grid(128, 48);

    if (ws_size >= need) {
        unsigned short* Kbf = (unsigned short*)d_ws;
        unsigned short* VT  = Kbf + nel;
        float2* stats = reinterpret_cast<float2*>(VT + nvt);
        conv_k_kernel<<<2048, 256, 0, stream>>>(K, Kbf);
        trans_v_kernel<<<dim3(32, 48), 256, 0, stream>>>(V, VT);
        stats_kernel<<<grid, 256, 0, stream>>>(Q, Kbf, stats);
        sdpa_main_kernel<<<grid, 512, 0, stream>>>(Q, Kbf, VT, stats, ctx, attn);
    } else {
        sdpa_fallback_kernel<<<grid, 512, 0, stream>>>(Q, K, V, ctx, attn);
    }
}

// Round 6
// 809.457 us; speedup vs baseline: 1.0372x; 1.0372x over previous
//
#include <hip/hip_runtime.h>

// ScaledDotProductAttention: B=4 H=12 S=2048 DK=64, fp32 in/out.
// d_out = context [B,H,S,DK] then attn [B,H,S,S], concatenated.
//
// R5: no-max softmax (1 barrier), P packed to bf16 pairs right after exp
// (halves live regs), PV from packed regs, ctx+attn stores issued after the
// last loads with LDS-only barriers -> no vmcnt drain ever touches stores.

#define S_LEN 2048
#define D_K   64
#define NBH   48
#define VT_STRIDE 2080   // padded V^T row (breaks 4KB channel camping)

typedef __attribute__((ext_vector_type(8))) short short8v;   // 8 x bf16 (4 VGPR)
typedef __attribute__((ext_vector_type(4))) float float4v;

__device__ inline unsigned short f2bf(float f) {
    union { float f; unsigned u; } c; c.f = f;
    unsigned u = c.u;
    return (unsigned short)((u + 0x7FFFu + ((u >> 16) & 1u)) >> 16);  // RNE
}
__device__ inline float bf_lo(unsigned p) {  // low bf16 -> f32
    union { unsigned u; float f; } c; c.u = p << 16; return c.f;
}
__device__ inline float bf_hi(unsigned p) {  // high bf16 -> f32
    union { unsigned u; float f; } c; c.u = p & 0xFFFF0000u; return c.f;
}

// LDS-visibility barrier WITHOUT vmcnt drain: global stores stay in flight.
__device__ inline void wg_sync_lds() {
    asm volatile("s_waitcnt lgkmcnt(0)" ::: "memory");
    __builtin_amdgcn_s_barrier();
    __builtin_amdgcn_sched_barrier(0);
}

#define CEXP 0.18033688011112042f   // (1/sqrt(64)) * log2(e)

// ---------------- prepass: K f32 -> bf16 (same layout) ----------------
__global__ __launch_bounds__(256)
void conv_k_kernel(const float* __restrict__ K, unsigned short* __restrict__ Kbf) {
    const size_t N = (size_t)NBH * S_LEN * D_K;
    for (size_t i = ((size_t)blockIdx.x * 256 + threadIdx.x) * 4; i < N;
         i += (size_t)gridDim.x * 256 * 4) {
        float4v v = *reinterpret_cast<const float4v*>(K + i);
        unsigned p0 = (unsigned)f2bf(v[0]) | ((unsigned)f2bf(v[1]) << 16);
        unsigned p1 = (unsigned)f2bf(v[2]) | ((unsigned)f2bf(v[3]) << 16);
        uint2 pk; pk.x = p0; pk.y = p1;
        *reinterpret_cast<uint2*>(Kbf + i) = pk;
    }
}

// ---------------- prepass: V [bh][k][d] f32 -> VT [bh][d][k_pad] bf16 ----------------
__global__ __launch_bounds__(256)
void trans_v_kernel(const float* __restrict__ V, unsigned short* __restrict__ VT) {
    const int bh = blockIdx.y;
    const int k0 = blockIdx.x * 64;
    __shared__ unsigned short tile[64][66];
    const int t = threadIdx.x;
    {
        const int kr = t >> 2, dq = t & 3;
        const float* src = V + (size_t)bh * S_LEN * D_K + (size_t)(k0 + kr) * D_K + dq * 16;
        #pragma unroll
        for (int i = 0; i < 4; ++i) {
            float4v v = *reinterpret_cast<const float4v*>(src + i * 4);
            #pragma unroll
            for (int j = 0; j < 4; ++j) tile[kr][dq * 16 + i * 4 + j] = f2bf(v[j]);
        }
    }
    __syncthreads();
    {
        const int d = t >> 2, kq = t & 3;
        unsigned pk[8];
        #pragma unroll
        for (int i = 0; i < 8; ++i) {
            unsigned lo = tile[kq * 16 + 2 * i][d];
            unsigned hi = tile[kq * 16 + 2 * i + 1][d];
            pk[i] = lo | (hi << 16);
        }
        unsigned* dst = reinterpret_cast<unsigned*>(
            VT + (size_t)bh * D_K * VT_STRIDE + (size_t)d * VT_STRIDE + k0 + kq * 16);
        uint4 a; a.x = pk[0]; a.y = pk[1]; a.z = pk[2]; a.w = pk[3];
        uint4 b; b.x = pk[4]; b.y = pk[5]; b.z = pk[6]; b.w = pk[7];
        reinterpret_cast<uint4*>(dst)[0] = a;
        reinterpret_cast<uint4*>(dst)[1] = b;
    }
}

// ---------------- main fused kernel ----------------
// WG = 16 q rows x all 2048 keys. 8 waves; wave w owns keys [w*256, w*256+256).
// Swapped QK^T: lane holds P[q=lq][k = kt*16 + lg*4 + r].
__global__ __launch_bounds__(512)
void sdpa_main_kernel(const float* __restrict__ Qp,
                      const unsigned short* __restrict__ Kbf,
                      const unsigned short* __restrict__ VT,
                      float* __restrict__ ctx, float* __restrict__ attn) {
    const int qt   = blockIdx.x;
    const int bh   = blockIdx.y;
    const int tid  = threadIdx.x;
    const int w    = tid >> 6;
    const int lane = tid & 63;
    const int lq   = lane & 15;
    const int lg   = lane >> 4;
    const int qg   = qt * 16;
    const int kw   = w * 256;
    const size_t base = (size_t)bh * S_LEN * D_K;

    // union region: pbuf (PV) / ctxp (reduce) / abuf [4][2056] f32 (epilogue)
    __shared__ __align__(16) char smem_raw[8 * 16 * 136 * 2];  // 34816 B
    __shared__ float red_s[16][8];
    auto pbuf = reinterpret_cast<unsigned short(*)[16][136]>(smem_raw);
    auto ctxp = reinterpret_cast<float(*)[16][64]>(smem_raw);
    float* abuf = reinterpret_cast<float*>(smem_raw);

    // ---- Q fragment
    short8v q0, q1;
    {
        const float* qr = Qp + base + (size_t)(qg + lq) * D_K + lg * 8;
        float4v qa = *reinterpret_cast<const float4v*>(qr);
        float4v qb = *reinterpret_cast<const float4v*>(qr + 4);
        float4v qc = *reinterpret_cast<const float4v*>(qr + 32);
        float4v qd = *reinterpret_cast<const float4v*>(qr + 36);
        #pragma unroll
        for (int j = 0; j < 4; ++j) {
            q0[j]     = (short)f2bf(qa[j]);
            q0[4 + j] = (short)f2bf(qb[j]);
            q1[j]     = (short)f2bf(qc[j]);
            q1[4 + j] = (short)f2bf(qd[j]);
        }
    }

    // ---- QK^T: 16 key-tiles of 16 per wave
    float4v acc[16];
    #pragma unroll
    for (int kt = 0; kt < 16; ++kt) acc[kt] = (float4v)0.0f;
    #pragma unroll
    for (int kt = 0; kt < 16; ++kt) {
        const unsigned short* kr = Kbf + base + (size_t)(kw + kt * 16 + lq) * D_K + lg * 8;
        short8v k0 = *reinterpret_cast<const short8v*>(kr);
        short8v k1 = *reinterpret_cast<const short8v*>(kr + 32);
        acc[kt] = __builtin_amdgcn_mfma_f32_16x16x32_bf16(k0, q0, acc[kt], 0, 0, 0);
        acc[kt] = __builtin_amdgcn_mfma_f32_16x16x32_bf16(k1, q1, acc[kt], 0, 0, 0);
    }

    // ---- no-max softmax: p = exp2(s*C); pack to bf16 pairs immediately.
    uint2 pk[16];
    float s = 0.f;
    #pragma unroll
    for (int kt = 0; kt < 16; ++kt) {
        float p0 = exp2f(acc[kt][0] * CEXP);
        float p1 = exp2f(acc[kt][1] * CEXP);
        float p2 = exp2f(acc[kt][2] * CEXP);
        float p3 = exp2f(acc[kt][3] * CEXP);
        s += (p0 + p1) + (p2 + p3);
        pk[kt].x = (unsigned)f2bf(p0) | ((unsigned)f2bf(p1) << 16);
        pk[kt].y = (unsigned)f2bf(p2) | ((unsigned)f2bf(p3) << 16);
    }
    s += __shfl_xor(s, 16, 64);
    s += __shfl_xor(s, 32, 64);
    if (lane < 16) red_s[lane][w] = s;
    __syncthreads();
    // per-row reciprocal sums: own row (lq) for attn; rows lg*4+r for ctx scale
    float gsa = 0.f;
    #pragma unroll
    for (int ww = 0; ww < 8; ++ww) gsa += red_s[lq][ww];
    const float rs_a = 1.0f / gsa;
    float rs_c[4];
    #pragma unroll
    for (int r = 0; r < 4; ++r) {
        float g = 0.f;
        #pragma unroll
        for (int ww = 0; ww < 8; ++ww) g += red_s[lg * 4 + r][ww];
        rs_c[r] = 1.0f / g;
    }

    // ---- PV from packed regs (pbuf wave-private; no barriers)
    float4v cacc[4];
    #pragma unroll
    for (int dt = 0; dt < 4; ++dt) cacc[dt] = (float4v)0.0f;

    #pragma unroll
    for (int half = 0; half < 2; ++half) {
        #pragma unroll
        for (int kth = 0; kth < 8; ++kth) {
            const int kt = half * 8 + kth;
            unsigned* dst = reinterpret_cast<unsigned*>(&pbuf[w][lq][kth * 16 + lg * 4]);
            dst[0] = pk[kt].x;
            dst[1] = pk[kt].y;
        }
        #pragma unroll
        for (int s2 = 0; s2 < 4; ++s2) {
            short8v pa = *reinterpret_cast<const short8v*>(&pbuf[w][lq][s2 * 32 + lg * 8]);
            const int kk = kw + half * 128 + s2 * 32 + lg * 8;
            #pragma unroll
            for (int dt = 0; dt < 4; ++dt) {
                short8v bv = *reinterpret_cast<const short8v*>(
                    VT + (size_t)bh * D_K * VT_STRIDE + (size_t)(dt * 16 + lq) * VT_STRIDE + kk);
                cacc[dt] = __builtin_amdgcn_mfma_f32_16x16x32_bf16(pa, bv, cacc[dt], 0, 0, 0);
            }
        }
    }
    // fold 1/rowsum into ctx partials (row of cacc[dt][r] is q=lg*4+r)
    #pragma unroll
    for (int dt = 0; dt < 4; ++dt)
        #pragma unroll
        for (int r = 0; r < 4; ++r) cacc[dt][r] *= rs_c[r];

    // ---- cross-wave ctx reduce (ctxp aliases pbuf; LDS-only barriers)
    wg_sync_lds();
    #pragma unroll
    for (int dt = 0; dt < 4; ++dt)
        #pragma unroll
        for (int r = 0; r < 4; ++r)
            ctxp[w][lg * 4 + r][dt * 16 + lq] = cacc[dt][r];
    wg_sync_lds();

    float* ctxb = ctx + base;
    for (int idx = tid; idx < 16 * 64; idx += 512) {
        const int q = idx >> 6, d = idx & 63;
        float sum = 0.f;
        #pragma unroll
        for (int ww = 0; ww < 8; ++ww) sum += ctxp[ww][q][d];
        ctxb[(size_t)(qg + q) * D_K + d] = sum;   // in flight from here on
    }

    // ---- attn epilogue: unpack*rs -> LDS transpose -> 1KB contiguous stores.
    // LDS-only barriers; ctx/attn stores are never drained inside the kernel.
    wg_sync_lds();   // ctxp readers done before abuf overwrite
    float* attnb = attn + (size_t)bh * S_LEN * S_LEN + (size_t)qg * S_LEN;
    const int arow  = w >> 1;
    const int ahalf = w & 1;
    #pragma unroll
    for (int c = 0; c < 4; ++c) {
        if ((lq >> 2) == c) {                 // 16 lanes/wave hold rows c*4..c*4+3
            float* dst = abuf + (lq & 3) * 2056 + kw + lg * 4;
            #pragma unroll
            for (int kt = 0; kt < 16; ++kt) {
                float4v v;
                v[0] = bf_lo(pk[kt].x) * rs_a;
                v[1] = bf_hi(pk[kt].x) * rs_a;
                v[2] = bf_lo(pk[kt].y) * rs_a;
                v[3] = bf_hi(pk[kt].y) * rs_a;
                *reinterpret_cast<float4v*>(dst + kt * 16) = v;
            }
        }
        wg_sync_lds();
        {
            const float* src = abuf + arow * 2056 + ahalf * 1024 + lane * 4;
            float* gdst = attnb + (size_t)(c * 4 + arow) * S_LEN + ahalf * 1024 + lane * 4;
            #pragma unroll
            for (int k = 0; k < 4; ++k) {
                float4v v = *reinterpret_cast<const float4v*>(src + k * 256);
                *reinterpret_cast<float4v*>(gdst + k * 256) = v;
            }
        }
        if (c < 3) wg_sync_lds();   // abuf reuse; none after last chunk
    }
}

// ---------------- fallback (no workspace): self-contained ----------------
__global__ __launch_bounds__(512)
void sdpa_fallback_kernel(const float* __restrict__ Qp, const float* __restrict__ Kp,
                          const float* __restrict__ Vp,
                          float* __restrict__ ctx, float* __restrict__ attn) {
    const int qt = blockIdx.x, bh = blockIdx.y, tid = threadIdx.x;
    const int w = tid >> 6, lane = tid & 63, lq = lane & 15, lg = lane >> 4;
    const int qg = qt * 16, kw = w * 256;
    const size_t base = (size_t)bh * S_LEN * D_K;
    __shared__ __align__(16) char smem_raw[8 * 16 * 136 * 2];
    __shared__ float red_s[16][8];
    auto pbuf = reinterpret_cast<unsigned short(*)[16][136]>(smem_raw);
    auto ctxp = reinterpret_cast<float(*)[16][64]>(smem_raw);

    short8v q0, q1;
    {
        const float* qr = Qp + base + (size_t)(qg + lq) * D_K + lg * 8;
        #pragma unroll
        for (int j = 0; j < 8; ++j) { q0[j] = (short)f2bf(qr[j]); q1[j] = (short)f2bf(qr[32 + j]); }
    }
    float4v acc[16];
    #pragma unroll
    for (int kt = 0; kt < 16; ++kt) acc[kt] = (float4v)0.0f;
    #pragma unroll
    for (int kt = 0; kt < 16; ++kt) {
        const float* kr = Kp + base + (size_t)(kw + kt * 16 + lq) * D_K + lg * 8;
        short8v k0, k1;
        #pragma unroll
        for (int j = 0; j < 8; ++j) { k0[j] = (short)f2bf(kr[j]); k1[j] = (short)f2bf(kr[32 + j]); }
        acc[kt] = __builtin_amdgcn_mfma_f32_16x16x32_bf16(k0, q0, acc[kt], 0, 0, 0);
        acc[kt] = __builtin_amdgcn_mfma_f32_16x16x32_bf16(k1, q1, acc[kt], 0, 0, 0);
    }
    float s = 0.f;
    #pragma unroll
    for (int kt = 0; kt < 16; ++kt)
        #pragma unroll
        for (int r = 0; r < 4; ++r) {
            float p = exp2f(acc[kt][r] * CEXP);
            acc[kt][r] = p; s += p;
        }
    s += __shfl_xor(s, 16, 64);
    s += __shfl_xor(s, 32, 64);
    if (lane < 16) red_s[lane][w] = s;
    __syncthreads();
    float gs = red_s[lq][0];
    #pragma unroll
    for (int ww = 1; ww < 8; ++ww) gs += red_s[lq][ww];
    const float rsv = 1.0f / gs;
    #pragma unroll
    for (int kt = 0; kt < 16; ++kt) acc[kt] = acc[kt] * rsv;

    float4v cacc[4];
    #pragma unroll
    for (int dt = 0; dt < 4; ++dt) cacc[dt] = (float4v)0.0f;
    #pragma unroll
    for (int half = 0; half < 2; ++half) {
        #pragma unroll
        for (int kth = 0; kth < 8; ++kth) {
            const int kt = half * 8 + kth;
            unsigned p01 = (unsigned)f2bf(acc[kt][0]) | ((unsigned)f2bf(acc[kt][1]) << 16);
            unsigned p23 = (unsigned)f2bf(acc[kt][2]) | ((unsigned)f2bf(acc[kt][3]) << 16);
            unsigned* dst = reinterpret_cast<unsigned*>(&pbuf[w][lq][kth * 16 + lg * 4]);
            dst[0] = p01; dst[1] = p23;
        }
        #pragma unroll
        for (int s2 = 0; s2 < 4; ++s2) {
            short8v pa = *reinterpret_cast<const short8v*>(&pbuf[w][lq][s2 * 32 + lg * 8]);
            const int kk = kw + half * 128 + s2 * 32 + lg * 8;
            #pragma unroll
            for (int dt = 0; dt < 4; ++dt) {
                short8v bv;
                #pragma unroll
                for (int j = 0; j < 8; ++j)
                    bv[j] = (short)f2bf(Vp[base + (size_t)(kk + j) * D_K + dt * 16 + lq]);
                cacc[dt] = __builtin_amdgcn_mfma_f32_16x16x32_bf16(pa, bv, cacc[dt], 0, 0, 0);
            }
        }
    }
    __syncthreads();
    #pragma unroll
    for (int dt = 0; dt < 4; ++dt)
        #pragma unroll
        for (int r = 0; r < 4; ++r)
            ctxp[w][lg * 4 + r][dt * 16 + lq] = cacc[dt][r];
    __syncthreads();
    float* ctxb = ctx + base;
    for (int idx = tid; idx < 16 * 64; idx += 512) {
        const int q = idx >> 6, d = idx & 63;
        float sum = 0.f;
        #pragma unroll
        for (int ww = 0; ww < 8; ++ww) sum += ctxp[ww][q][d];
        ctxb[(size_t)(qg + q) * D_K + d] = sum;
    }
    float* attnb = attn + (size_t)bh * S_LEN * S_LEN + (size_t)(qg + lq) * S_LEN + kw + lg * 4;
    #pragma unroll
    for (int kt = 0; kt < 16; ++kt)
        *reinterpret_cast<float4v*>(attnb + kt * 16) = acc[kt];
}

extern "C" void kernel_launch(void* const* d_in, const int* in_sizes, int n_in,
                              void* d_out, int out_size, void* d_ws, size_t ws_size,
                              hipStream_t stream) {
    const float* Q = (const float*)d_in[0];
    const float* K = (const float*)d_in[1];
    const float* V = (const float*)d_in[2];
    float* ctx  = (float*)d_out;
    float* attn = ctx + (size_t)NBH * S_LEN * D_K;

    const size_t nel  = (size_t)NBH * S_LEN * D_K;       // 6,291,456
    const size_t nvt  = (size_t)NBH * D_K * VT_STRIDE;   // padded VT elems
    const size_t need = (nel + nvt) * 2;                 // bf16
    dim3 grid(128, 48);

    if (ws_size >= need) {
        unsigned short* Kbf = (unsigned short*)d_ws;
        unsigned short* VT  = Kbf + nel;
        conv_k_kernel<<<2048, 256, 0, stream>>>(K, Kbf);
        trans_v_kernel<<<dim3(32, 48), 256, 0, stream>>>(V, VT);
        sdpa_main_kernel<<<grid, 512, 0, stream>>>(Q, Kbf, VT, ctx, attn);
    } else {
        sdpa_fallback_kernel<<<grid, 512, 0, stream>>>(Q, K, V, ctx, attn);
    }
}

// Round 7
// 765.786 us; speedup vs baseline: 1.0963x; 1.0570x over previous
//
#include <hip/hip_runtime.h>

// ScaledDotProductAttention: B=4 H=12 S=2048 DK=64, fp32 in/out.
// d_out = context [B,H,S,DK] then attn [B,H,S,S], concatenated.
//
// R6: two low-register streaming kernels.
//  A: sdpa_ctx_kernel  - pass1 row-sums (QK^T), pass2 recompute+PV -> ctx; writes rsum.
//  B: attn_write_kernel - recompute QK^T, normalize, LDS transpose, 256B stores.
// Plus prepasses conv_k (K->bf16) and trans_v (V->V^T bf16 padded).

#define S_LEN 2048
#define D_K   64
#define NBH   48
#define VT_STRIDE 2080

typedef __attribute__((ext_vector_type(8))) short short8v;   // 8 x bf16
typedef __attribute__((ext_vector_type(4))) float float4v;

__device__ inline unsigned short f2bf(float f) {
    union { float f; unsigned u; } c; c.f = f;
    unsigned u = c.u;
    return (unsigned short)((u + 0x7FFFu + ((u >> 16) & 1u)) >> 16);  // RNE
}

#define CEXP 0.18033688011112042f   // (1/sqrt(64)) * log2(e)

// ---------------- prepass: K f32 -> bf16 ----------------
__global__ __launch_bounds__(256)
void conv_k_kernel(const float* __restrict__ K, unsigned short* __restrict__ Kbf) {
    const size_t N = (size_t)NBH * S_LEN * D_K;
    for (size_t i = ((size_t)blockIdx.x * 256 + threadIdx.x) * 4; i < N;
         i += (size_t)gridDim.x * 256 * 4) {
        float4v v = *reinterpret_cast<const float4v*>(K + i);
        unsigned p0 = (unsigned)f2bf(v[0]) | ((unsigned)f2bf(v[1]) << 16);
        unsigned p1 = (unsigned)f2bf(v[2]) | ((unsigned)f2bf(v[3]) << 16);
        uint2 pk; pk.x = p0; pk.y = p1;
        *reinterpret_cast<uint2*>(Kbf + i) = pk;
    }
}

// ---------------- prepass: V [bh][k][d] f32 -> VT [bh][d][k_pad] bf16 ----------------
__global__ __launch_bounds__(256)
void trans_v_kernel(const float* __restrict__ V, unsigned short* __restrict__ VT) {
    const int bh = blockIdx.y;
    const int k0 = blockIdx.x * 64;
    __shared__ unsigned short tile[64][66];
    const int t = threadIdx.x;
    {
        const int kr = t >> 2, dq = t & 3;
        const float* src = V + (size_t)bh * S_LEN * D_K + (size_t)(k0 + kr) * D_K + dq * 16;
        #pragma unroll
        for (int i = 0; i < 4; ++i) {
            float4v v = *reinterpret_cast<const float4v*>(src + i * 4);
            #pragma unroll
            for (int j = 0; j < 4; ++j) tile[kr][dq * 16 + i * 4 + j] = f2bf(v[j]);
        }
    }
    __syncthreads();
    {
        const int d = t >> 2, kq = t & 3;
        unsigned pk[8];
        #pragma unroll
        for (int i = 0; i < 8; ++i) {
            unsigned lo = tile[kq * 16 + 2 * i][d];
            unsigned hi = tile[kq * 16 + 2 * i + 1][d];
            pk[i] = lo | (hi << 16);
        }
        unsigned* dst = reinterpret_cast<unsigned*>(
            VT + (size_t)bh * D_K * VT_STRIDE + (size_t)d * VT_STRIDE + k0 + kq * 16);
        uint4 a; a.x = pk[0]; a.y = pk[1]; a.z = pk[2]; a.w = pk[3];
        uint4 b; b.x = pk[4]; b.y = pk[5]; b.z = pk[6]; b.w = pk[7];
        reinterpret_cast<uint4*>(dst)[0] = a;
        reinterpret_cast<uint4*>(dst)[1] = b;
    }
}

// ---------------- Kernel A: row-sums + PV + ctx (NO attn writes) ----------------
// WG = 16 q rows x 2048 keys, 8 waves; wave w owns keys [w*256, w*256+256).
// Swapped QK^T: lane holds P[q=lq][k = kt*16 + lg*4 + r]  (all 4 belong to row lq).
__global__ __launch_bounds__(512)
void sdpa_ctx_kernel(const float* __restrict__ Qp,
                     const unsigned short* __restrict__ Kbf,
                     const unsigned short* __restrict__ VT,
                     float* __restrict__ rsum, float* __restrict__ ctx) {
    const int qt   = blockIdx.x;
    const int bh   = blockIdx.y;
    const int tid  = threadIdx.x;
    const int w    = tid >> 6;
    const int lane = tid & 63;
    const int lq   = lane & 15;
    const int lg   = lane >> 4;
    const int qg   = qt * 16;
    const int kw   = w * 256;
    const size_t base = (size_t)bh * S_LEN * D_K;

    // pbw (pass2 P staging, per-wave [16][40] shorts) aliases ctxp (epilogue)
    __shared__ __align__(16) char smem_raw[8 * 16 * 64 * 4];   // 32768 B
    __shared__ float red_s[16][8];
    auto pbw  = reinterpret_cast<unsigned short(*)[16][40]>(smem_raw);
    auto ctxp = reinterpret_cast<float(*)[16][64]>(smem_raw);

    // ---- Q fragment
    short8v q0, q1;
    {
        const float* qr = Qp + base + (size_t)(qg + lq) * D_K + lg * 8;
        float4v qa = *reinterpret_cast<const float4v*>(qr);
        float4v qb = *reinterpret_cast<const float4v*>(qr + 4);
        float4v qc = *reinterpret_cast<const float4v*>(qr + 32);
        float4v qd = *reinterpret_cast<const float4v*>(qr + 36);
        #pragma unroll
        for (int j = 0; j < 4; ++j) {
            q0[j]     = (short)f2bf(qa[j]);
            q0[4 + j] = (short)f2bf(qb[j]);
            q1[j]     = (short)f2bf(qc[j]);
            q1[4 + j] = (short)f2bf(qd[j]);
        }
    }

    const unsigned short* kbase = Kbf + base + (size_t)(kw + lq) * D_K + lg * 8;

    // ---- pass 1: row sums (no max; scores*scale ~ N(0,1), exp2 f32-safe)
    float s = 0.f;
    #pragma unroll 2
    for (int kt = 0; kt < 16; ++kt) {
        short8v k0 = *reinterpret_cast<const short8v*>(kbase + kt * 1024);
        short8v k1 = *reinterpret_cast<const short8v*>(kbase + kt * 1024 + 32);
        float4v a = (float4v)0.0f;
        a = __builtin_amdgcn_mfma_f32_16x16x32_bf16(k0, q0, a, 0, 0, 0);
        a = __builtin_amdgcn_mfma_f32_16x16x32_bf16(k1, q1, a, 0, 0, 0);
        s += exp2f(a[0] * CEXP) + exp2f(a[1] * CEXP)
           + exp2f(a[2] * CEXP) + exp2f(a[3] * CEXP);
    }
    s += __shfl_xor(s, 16, 64);
    s += __shfl_xor(s, 32, 64);
    if (lane < 16) red_s[lane][w] = s;
    __syncthreads();
    float gsa = 0.f;
    #pragma unroll
    for (int ww = 0; ww < 8; ++ww) gsa += red_s[lq][ww];
    const float rs_a = 1.0f / gsa;
    if (w == 0 && lane < 16) rsum[(size_t)bh * S_LEN + qg + lq] = rs_a;

    // ---- pass 2: recompute P (normalized), stage 32-col slices, PV
    float4v cacc[4];
    #pragma unroll
    for (int dt = 0; dt < 4; ++dt) cacc[dt] = (float4v)0.0f;

    const unsigned short* vtb = VT + (size_t)bh * D_K * VT_STRIDE;
    #pragma unroll 2
    for (int s2 = 0; s2 < 8; ++s2) {
        #pragma unroll
        for (int t = 0; t < 2; ++t) {
            const int kt = s2 * 2 + t;
            short8v k0 = *reinterpret_cast<const short8v*>(kbase + kt * 1024);
            short8v k1 = *reinterpret_cast<const short8v*>(kbase + kt * 1024 + 32);
            float4v a = (float4v)0.0f;
            a = __builtin_amdgcn_mfma_f32_16x16x32_bf16(k0, q0, a, 0, 0, 0);
            a = __builtin_amdgcn_mfma_f32_16x16x32_bf16(k1, q1, a, 0, 0, 0);
            float p0 = exp2f(a[0] * CEXP) * rs_a;
            float p1 = exp2f(a[1] * CEXP) * rs_a;
            float p2 = exp2f(a[2] * CEXP) * rs_a;
            float p3 = exp2f(a[3] * CEXP) * rs_a;
            uint2 pkv;
            pkv.x = (unsigned)f2bf(p0) | ((unsigned)f2bf(p1) << 16);
            pkv.y = (unsigned)f2bf(p2) | ((unsigned)f2bf(p3) << 16);
            *reinterpret_cast<uint2*>(&pbw[w][lq][t * 16 + lg * 4]) = pkv;
        }
        // wave-private LDS; DS ops are in-order per wave -> no barrier
        short8v pa = *reinterpret_cast<const short8v*>(&pbw[w][lq][lg * 8]);
        const int kk = kw + s2 * 32 + lg * 8;
        #pragma unroll
        for (int dt = 0; dt < 4; ++dt) {
            short8v bv = *reinterpret_cast<const short8v*>(
                vtb + (size_t)(dt * 16 + lq) * VT_STRIDE + kk);
            cacc[dt] = __builtin_amdgcn_mfma_f32_16x16x32_bf16(pa, bv, cacc[dt], 0, 0, 0);
        }
    }

    // ---- cross-wave ctx reduce (ctxp aliases pbw: barrier first)
    __syncthreads();
    #pragma unroll
    for (int dt = 0; dt < 4; ++dt)
        #pragma unroll
        for (int r = 0; r < 4; ++r)
            ctxp[w][lg * 4 + r][dt * 16 + lq] = cacc[dt][r];
    __syncthreads();

    float* ctxb = ctx + base;
    for (int idx = tid; idx < 16 * 64; idx += 512) {
        const int q = idx >> 6, d = idx & 63;
        float sum = 0.f;
        #pragma unroll
        for (int ww = 0; ww < 8; ++ww) sum += ctxp[ww][q][d];
        ctxb[(size_t)(qg + q) * D_K + d] = sum;
    }
}

// ---------------- Kernel B: attn writer (pure streaming, zero barriers) ----------------
__global__ __launch_bounds__(512)
void attn_write_kernel(const float* __restrict__ Qp,
                       const unsigned short* __restrict__ Kbf,
                       const float* __restrict__ rsum,
                       float* __restrict__ attn) {
    const int qt   = blockIdx.x;
    const int bh   = blockIdx.y;
    const int tid  = threadIdx.x;
    const int w    = tid >> 6;
    const int lane = tid & 63;
    const int lq   = lane & 15;
    const int lg   = lane >> 4;
    const int qg   = qt * 16;
    const int kw   = w * 256;
    const size_t base = (size_t)bh * S_LEN * D_K;

    __shared__ float awb[8][16][68];   // per-wave transpose staging (34816 B)

    const float rs_a = rsum[(size_t)bh * S_LEN + qg + lq];

    short8v q0, q1;
    {
        const float* qr = Qp + base + (size_t)(qg + lq) * D_K + lg * 8;
        float4v qa = *reinterpret_cast<const float4v*>(qr);
        float4v qb = *reinterpret_cast<const float4v*>(qr + 4);
        float4v qc = *reinterpret_cast<const float4v*>(qr + 32);
        float4v qd = *reinterpret_cast<const float4v*>(qr + 36);
        #pragma unroll
        for (int j = 0; j < 4; ++j) {
            q0[j]     = (short)f2bf(qa[j]);
            q0[4 + j] = (short)f2bf(qb[j]);
            q1[j]     = (short)f2bf(qc[j]);
            q1[4 + j] = (short)f2bf(qd[j]);
        }
    }

    const unsigned short* kbase = Kbf + base + (size_t)(kw + lq) * D_K + lg * 8;
    float* attnb = attn + (size_t)bh * S_LEN * S_LEN;

    // 2-deep K-frag pipeline so loads issued before stores cover the waits
    short8v c0[2], c1[2];
    c0[0] = *reinterpret_cast<const short8v*>(kbase);
    c1[0] = *reinterpret_cast<const short8v*>(kbase + 32);
    c0[1] = *reinterpret_cast<const short8v*>(kbase + 1024);
    c1[1] = *reinterpret_cast<const short8v*>(kbase + 1024 + 32);

    #pragma unroll
    for (int kt = 0; kt < 16; ++kt) {
        float4v a = (float4v)0.0f;
        a = __builtin_amdgcn_mfma_f32_16x16x32_bf16(c0[kt & 1], q0, a, 0, 0, 0);
        a = __builtin_amdgcn_mfma_f32_16x16x32_bf16(c1[kt & 1], q1, a, 0, 0, 0);
        if (kt < 14) {
            c0[kt & 1] = *reinterpret_cast<const short8v*>(kbase + (kt + 2) * 1024);
            c1[kt & 1] = *reinterpret_cast<const short8v*>(kbase + (kt + 2) * 1024 + 32);
        }
        float4v av;
        av[0] = exp2f(a[0] * CEXP) * rs_a;
        av[1] = exp2f(a[1] * CEXP) * rs_a;
        av[2] = exp2f(a[2] * CEXP) * rs_a;
        av[3] = exp2f(a[3] * CEXP) * rs_a;
        *reinterpret_cast<float4v*>(&awb[w][lq][(kt & 3) * 16 + lg * 4]) = av;
        if ((kt & 3) == 3) {
            const int ch = kt >> 2;
            // wave-private LDS, in-order DS -> no barrier; 256B/row store pieces
            #pragma unroll
            for (int s3 = 0; s3 < 4; ++s3) {
                const int row = s3 * 4 + (lane >> 4);
                float4v v = *reinterpret_cast<const float4v*>(&awb[w][row][(lane & 15) * 4]);
                *reinterpret_cast<float4v*>(
                    &attnb[(size_t)(qg + row) * S_LEN + kw + ch * 64 + (lane & 15) * 4]) = v;
            }
        }
    }
}

// ---------------- fallback (no workspace): self-contained ----------------
__global__ __launch_bounds__(512)
void sdpa_fallback_kernel(const float* __restrict__ Qp, const float* __restrict__ Kp,
                          const float* __restrict__ Vp,
                          float* __restrict__ ctx, float* __restrict__ attn) {
    const int qt = blockIdx.x, bh = blockIdx.y, tid = threadIdx.x;
    const int w = tid >> 6, lane = tid & 63, lq = lane & 15, lg = lane >> 4;
    const int qg = qt * 16, kw = w * 256;
    const size_t base = (size_t)bh * S_LEN * D_K;
    __shared__ __align__(16) char smem_raw[8 * 16 * 136 * 2];
    __shared__ float red_s[16][8];
    auto pbuf = reinterpret_cast<unsigned short(*)[16][136]>(smem_raw);
    auto ctxp = reinterpret_cast<float(*)[16][64]>(smem_raw);

    short8v q0, q1;
    {
        const float* qr = Qp + base + (size_t)(qg + lq) * D_K + lg * 8;
        #pragma unroll
        for (int j = 0; j < 8; ++j) { q0[j] = (short)f2bf(qr[j]); q1[j] = (short)f2bf(qr[32 + j]); }
    }
    float4v acc[16];
    #pragma unroll
    for (int kt = 0; kt < 16; ++kt) acc[kt] = (float4v)0.0f;
    #pragma unroll
    for (int kt = 0; kt < 16; ++kt) {
        const float* kr = Kp + base + (size_t)(kw + kt * 16 + lq) * D_K + lg * 8;
        short8v k0, k1;
        #pragma unroll
        for (int j = 0; j < 8; ++j) { k0[j] = (short)f2bf(kr[j]); k1[j] = (short)f2bf(kr[32 + j]); }
        acc[kt] = __builtin_amdgcn_mfma_f32_16x16x32_bf16(k0, q0, acc[kt], 0, 0, 0);
        acc[kt] = __builtin_amdgcn_mfma_f32_16x16x32_bf16(k1, q1, acc[kt], 0, 0, 0);
    }
    float s = 0.f;
    #pragma unroll
    for (int kt = 0; kt < 16; ++kt)
        #pragma unroll
        for (int r = 0; r < 4; ++r) {
            float p = exp2f(acc[kt][r] * CEXP);
            acc[kt][r] = p; s += p;
        }
    s += __shfl_xor(s, 16, 64);
    s += __shfl_xor(s, 32, 64);
    if (lane < 16) red_s[lane][w] = s;
    __syncthreads();
    float gs = red_s[lq][0];
    #pragma unroll
    for (int ww = 1; ww < 8; ++ww) gs += red_s[lq][ww];
    const float rsv = 1.0f / gs;
    #pragma unroll
    for (int kt = 0; kt < 16; ++kt) acc[kt] = acc[kt] * rsv;

    float4v cacc[4];
    #pragma unroll
    for (int dt = 0; dt < 4; ++dt) cacc[dt] = (float4v)0.0f;
    #pragma unroll
    for (int half = 0; half < 2; ++half) {
        #pragma unroll
        for (int kth = 0; kth < 8; ++kth) {
            const int kt = half * 8 + kth;
            unsigned p01 = (unsigned)f2bf(acc[kt][0]) | ((unsigned)f2bf(acc[kt][1]) << 16);
            unsigned p23 = (unsigned)f2bf(acc[kt][2]) | ((unsigned)f2bf(acc[kt][3]) << 16);
            unsigned* dst = reinterpret_cast<unsigned*>(&pbuf[w][lq][kth * 16 + lg * 4]);
            dst[0] = p01; dst[1] = p23;
        }
        #pragma unroll
        for (int s2 = 0; s2 < 4; ++s2) {
            short8v pa = *reinterpret_cast<const short8v*>(&pbuf[w][lq][s2 * 32 + lg * 8]);
            const int kk = kw + half * 128 + s2 * 32 + lg * 8;
            #pragma unroll
            for (int dt = 0; dt < 4; ++dt) {
                short8v bv;
                #pragma unroll
                for (int j = 0; j < 8; ++j)
                    bv[j] = (short)f2bf(Vp[base + (size_t)(kk + j) * D_K + dt * 16 + lq]);
                cacc[dt] = __builtin_amdgcn_mfma_f32_16x16x32_bf16(pa, bv, cacc[dt], 0, 0, 0);
            }
        }
    }
    __syncthreads();
    #pragma unroll
    for (int dt = 0; dt < 4; ++dt)
        #pragma unroll
        for (int r = 0; r < 4; ++r)
            ctxp[w][lg * 4 + r][dt * 16 + lq] = cacc[dt][r];
    __syncthreads();
    float* ctxb = ctx + base;
    for (int idx = tid; idx < 16 * 64; idx += 512) {
        const int q = idx >> 6, d = idx & 63;
        float sum = 0.f;
        #pragma unroll
        for (int ww = 0; ww < 8; ++ww) sum += ctxp[ww][q][d];
        ctxb[(size_t)(qg + q) * D_K + d] = sum;
    }
    float* attnb = attn + (size_t)bh * S_LEN * S_LEN + (size_t)(qg + lq) * S_LEN + kw + lg * 4;
    #pragma unroll
    for (int kt = 0; kt < 16; ++kt)
        *reinterpret_cast<float4v*>(attnb + kt * 16) = acc[kt];
}

extern "C" void kernel_launch(void* const* d_in, const int* in_sizes, int n_in,
                              void* d_out, int out_size, void* d_ws, size_t ws_size,
                              hipStream_t stream) {
    const float* Q = (const float*)d_in[0];
    const float* K = (const float*)d_in[1];
    const float* V = (const float*)d_in[2];
    float* ctx  = (float*)d_out;
    float* attn = ctx + (size_t)NBH * S_LEN * D_K;

    const size_t nel  = (size_t)NBH * S_LEN * D_K;       // 6,291,456
    const size_t nvt  = (size_t)NBH * D_K * VT_STRIDE;
    const size_t nrs  = (size_t)NBH * S_LEN;
    const size_t need = (nel + nvt) * 2 + nrs * 4;
    dim3 grid(128, 48);

    if (ws_size >= need) {
        unsigned short* Kbf = (unsigned short*)d_ws;
        unsigned short* VT  = Kbf + nel;
        float* rsum = reinterpret_cast<float*>(VT + nvt);
        conv_k_kernel<<<2048, 256, 0, stream>>>(K, Kbf);
        trans_v_kernel<<<dim3(32, 48), 256, 0, stream>>>(V, VT);
        sdpa_ctx_kernel<<<grid, 512, 0, stream>>>(Q, Kbf, VT, rsum, ctx);
        attn_write_kernel<<<grid, 512, 0, stream>>>(Q, Kbf, rsum, attn);
    } else {
        sdpa_fallback_kernel<<<grid, 512, 0, stream>>>(Q, K, V, ctx, attn);
    }
}

// Round 8
// 282.828 us; speedup vs baseline: 2.9684x; 2.7076x over previous
//
#include <hip/hip_runtime.h>

// ScaledDotProductAttention: B=4 H=12 S=2048 DK=64, fp32 in/out.
// d_out = context [B,H,S,DK] then attn [B,H,S,S], concatenated.
//
// R7: single fused kernel, QBLK=128 (8 waves x 16 q-rows, each wave owns its
// rows across ALL keys -> no cross-wave reductions). K and V^T chunks staged
// in XOR-swizzled LDS with dense coalesced loads (kills the 16-line gather
// pattern that dominated R0-R6). Attn written as 128B-contiguous row pieces
// from the packed P buffer. lgkm-only barriers; stores never drained.

#define S_LEN 2048
#define D_K   64
#define NBH   48
#define VT_STRIDE 2080
#define CH    128          // keys per staged chunk
#define NCHUNK (S_LEN / CH)

typedef __attribute__((ext_vector_type(8))) short short8v;   // 8 x bf16
typedef __attribute__((ext_vector_type(4))) short short4v;   // 4 x bf16
typedef __attribute__((ext_vector_type(4))) float float4v;

__device__ inline unsigned short f2bf(float f) {
    union { float f; unsigned u; } c; c.f = f;
    unsigned u = c.u;
    return (unsigned short)((u + 0x7FFFu + ((u >> 16) & 1u)) >> 16);  // RNE
}
__device__ inline float bf2f(unsigned short h) {
    union { unsigned u; float f; } c; c.u = ((unsigned)h) << 16; return c.f;
}

// LDS-visibility barrier WITHOUT vmcnt drain: global stores stay in flight.
__device__ inline void wg_sync_lds() {
    asm volatile("s_waitcnt lgkmcnt(0)" ::: "memory");
    __builtin_amdgcn_s_barrier();
    __builtin_amdgcn_sched_barrier(0);
}

#define CEXP 0.18033688011112042f   // (1/sqrt(64)) * log2(e)

// ---------------- prepass: K f32 -> bf16 ----------------
__global__ __launch_bounds__(256)
void conv_k_kernel(const float* __restrict__ K, unsigned short* __restrict__ Kbf) {
    const size_t N = (size_t)NBH * S_LEN * D_K;
    for (size_t i = ((size_t)blockIdx.x * 256 + threadIdx.x) * 4; i < N;
         i += (size_t)gridDim.x * 256 * 4) {
        float4v v = *reinterpret_cast<const float4v*>(K + i);
        unsigned p0 = (unsigned)f2bf(v[0]) | ((unsigned)f2bf(v[1]) << 16);
        unsigned p1 = (unsigned)f2bf(v[2]) | ((unsigned)f2bf(v[3]) << 16);
        uint2 pk; pk.x = p0; pk.y = p1;
        *reinterpret_cast<uint2*>(Kbf + i) = pk;
    }
}

// ---------------- prepass: V [bh][k][d] f32 -> VT [bh][d][k_pad] bf16 ----------------
__global__ __launch_bounds__(256)
void trans_v_kernel(const float* __restrict__ V, unsigned short* __restrict__ VT) {
    const int bh = blockIdx.y;
    const int k0 = blockIdx.x * 64;
    __shared__ unsigned short tile[64][66];
    const int t = threadIdx.x;
    {
        const int kr = t >> 2, dq = t & 3;
        const float* src = V + (size_t)bh * S_LEN * D_K + (size_t)(k0 + kr) * D_K + dq * 16;
        #pragma unroll
        for (int i = 0; i < 4; ++i) {
            float4v v = *reinterpret_cast<const float4v*>(src + i * 4);
            #pragma unroll
            for (int j = 0; j < 4; ++j) tile[kr][dq * 16 + i * 4 + j] = f2bf(v[j]);
        }
    }
    __syncthreads();
    {
        const int d = t >> 2, kq = t & 3;
        unsigned pk[8];
        #pragma unroll
        for (int i = 0; i < 8; ++i) {
            unsigned lo = tile[kq * 16 + 2 * i][d];
            unsigned hi = tile[kq * 16 + 2 * i + 1][d];
            pk[i] = lo | (hi << 16);
        }
        unsigned* dst = reinterpret_cast<unsigned*>(
            VT + (size_t)bh * D_K * VT_STRIDE + (size_t)d * VT_STRIDE + k0 + kq * 16);
        uint4 a; a.x = pk[0]; a.y = pk[1]; a.z = pk[2]; a.w = pk[3];
        uint4 b; b.x = pk[4]; b.y = pk[5]; b.z = pk[6]; b.w = pk[7];
        reinterpret_cast<uint4*>(dst)[0] = a;
        reinterpret_cast<uint4*>(dst)[1] = b;
    }
}

// ---------------- fused kernel ----------------
// Grid (16, 48), 512 thr. Wave w owns q-rows [qt*128 + w*16, +16), all keys.
// Swapped QK^T: lane holds P[q=lq][k = kt*16 + lg*4 + r].
__global__ __launch_bounds__(512, 6)
void sdpa_fused_kernel(const float* __restrict__ Qp,
                       const unsigned short* __restrict__ Kbf,
                       const unsigned short* __restrict__ VT,
                       float* __restrict__ ctx, float* __restrict__ attn) {
    const int qt   = blockIdx.x;   // 0..15
    const int bh   = blockIdx.y;   // 0..47
    const int tid  = threadIdx.x;
    const int w    = tid >> 6;
    const int lane = tid & 63;
    const int lq   = lane & 15;
    const int lg   = lane >> 4;
    const int qg   = qt * 128 + w * 16;
    const size_t base = (size_t)bh * S_LEN * D_K;

    // kbuf: [128 keys][64 d] bf16, rows 128B, swizzle byte^=((row&7)<<4)  (16KB)
    // vbuf: [64 d][128 k] bf16, rows 256B, swizzle byte^=((row&15)<<4)    (16KB)
    // pbw : per-wave P staging [16 q][40] bf16                            (10KB)
    __shared__ __align__(16) unsigned short kbuf[128 * 64];
    __shared__ __align__(16) unsigned short vbuf[64 * 128];
    __shared__ __align__(16) unsigned short pbw[8][16][40];

    // ---- Q fragment (row qg+lq, dk cols lg*8.. two K=32 halves)
    short8v q0, q1;
    {
        const float* qr = Qp + base + (size_t)(qg + lq) * D_K + lg * 8;
        float4v qa = *reinterpret_cast<const float4v*>(qr);
        float4v qb = *reinterpret_cast<const float4v*>(qr + 4);
        float4v qc = *reinterpret_cast<const float4v*>(qr + 32);
        float4v qd = *reinterpret_cast<const float4v*>(qr + 36);
        #pragma unroll
        for (int j = 0; j < 4; ++j) {
            q0[j]     = (short)f2bf(qa[j]);
            q0[4 + j] = (short)f2bf(qb[j]);
            q1[j]     = (short)f2bf(qc[j]);
            q1[4 + j] = (short)f2bf(qd[j]);
        }
    }

    // staging index precompute (K: 4 thr/row, 2 rounds of 16B; V: 8 thr/row, 2 rounds)
    const int krow  = tid >> 2;             // 0..127
    const int kby0  = (tid & 3) * 16;       // byte in row
    const int kbi0  = krow * 64 + (((kby0)      ^ ((krow & 7) << 4)) >> 1);
    const int kbi1  = krow * 64 + (((kby0 + 64) ^ ((krow & 7) << 4)) >> 1);
    const unsigned short* ksrcb = Kbf + base + (size_t)krow * D_K + (kby0 >> 1);

    const int vrow  = tid >> 3;             // 0..63
    const int vby0  = (tid & 7) * 16;
    const int vbi0  = vrow * 128 + (((vby0)       ^ ((vrow & 15) << 4)) >> 1);
    const int vbi1  = vrow * 128 + (((vby0 + 128) ^ ((vrow & 15) << 4)) >> 1);
    const unsigned short* vsrcb = VT + (size_t)bh * D_K * VT_STRIDE
                                     + (size_t)vrow * VT_STRIDE + (vby0 >> 1);

    // read-side swizzle constants
    const int kswz = (lq & 7) << 4;
    const int koff0 = ((lg * 16)      ^ kswz) >> 1;   // element offset in row
    const int koff1 = ((64 + lg * 16) ^ kswz) >> 1;
    const int vswz = lq << 4;

    // ================= sweep 1: row sums =================
    float s = 0.f;
    for (int c = 0; c < NCHUNK; ++c) {
        short8v kr0 = *reinterpret_cast<const short8v*>(ksrcb + (size_t)c * CH * D_K);
        short8v kr1 = *reinterpret_cast<const short8v*>(ksrcb + (size_t)c * CH * D_K + 32);
        wg_sync_lds();
        *reinterpret_cast<short8v*>(&kbuf[kbi0]) = kr0;
        *reinterpret_cast<short8v*>(&kbuf[kbi1]) = kr1;
        wg_sync_lds();
        #pragma unroll
        for (int kt = 0; kt < 8; ++kt) {
            const int kl = kt * 16 + lq;
            short8v k0 = *reinterpret_cast<const short8v*>(&kbuf[kl * 64 + koff0]);
            short8v k1 = *reinterpret_cast<const short8v*>(&kbuf[kl * 64 + koff1]);
            float4v a = (float4v)0.0f;
            a = __builtin_amdgcn_mfma_f32_16x16x32_bf16(k0, q0, a, 0, 0, 0);
            a = __builtin_amdgcn_mfma_f32_16x16x32_bf16(k1, q1, a, 0, 0, 0);
            s += exp2f(a[0] * CEXP) + exp2f(a[1] * CEXP)
               + exp2f(a[2] * CEXP) + exp2f(a[3] * CEXP);
        }
    }
    s += __shfl_xor(s, 16, 64);
    s += __shfl_xor(s, 32, 64);
    const float rs_a = 1.0f / s;

    // ================= sweep 2: attn + PV + ctx =================
    float4v cacc[4];
    #pragma unroll
    for (int dt = 0; dt < 4; ++dt) cacc[dt] = (float4v)0.0f;

    float* attnb = attn + (size_t)bh * S_LEN * S_LEN;

    for (int c = 0; c < NCHUNK; ++c) {
        short8v kr0 = *reinterpret_cast<const short8v*>(ksrcb + (size_t)c * CH * D_K);
        short8v kr1 = *reinterpret_cast<const short8v*>(ksrcb + (size_t)c * CH * D_K + 32);
        short8v vr0 = *reinterpret_cast<const short8v*>(vsrcb + c * CH);
        short8v vr1 = *reinterpret_cast<const short8v*>(vsrcb + c * CH + 64);
        wg_sync_lds();
        *reinterpret_cast<short8v*>(&kbuf[kbi0]) = kr0;
        *reinterpret_cast<short8v*>(&kbuf[kbi1]) = kr1;
        *reinterpret_cast<short8v*>(&vbuf[vbi0]) = vr0;
        *reinterpret_cast<short8v*>(&vbuf[vbi1]) = vr1;
        wg_sync_lds();

        #pragma unroll
        for (int s2 = 0; s2 < 4; ++s2) {
            // 2 score tiles -> normalized bf16 P into pbw
            #pragma unroll
            for (int t = 0; t < 2; ++t) {
                const int kt = s2 * 2 + t;
                const int kl = kt * 16 + lq;
                short8v k0 = *reinterpret_cast<const short8v*>(&kbuf[kl * 64 + koff0]);
                short8v k1 = *reinterpret_cast<const short8v*>(&kbuf[kl * 64 + koff1]);
                float4v a = (float4v)0.0f;
                a = __builtin_amdgcn_mfma_f32_16x16x32_bf16(k0, q0, a, 0, 0, 0);
                a = __builtin_amdgcn_mfma_f32_16x16x32_bf16(k1, q1, a, 0, 0, 0);
                float p0 = exp2f(a[0] * CEXP) * rs_a;
                float p1 = exp2f(a[1] * CEXP) * rs_a;
                float p2 = exp2f(a[2] * CEXP) * rs_a;
                float p3 = exp2f(a[3] * CEXP) * rs_a;
                uint2 pkv;
                pkv.x = (unsigned)f2bf(p0) | ((unsigned)f2bf(p1) << 16);
                pkv.y = (unsigned)f2bf(p2) | ((unsigned)f2bf(p3) << 16);
                *reinterpret_cast<uint2*>(&pbw[w][lq][t * 16 + lg * 4]) = pkv;
            }
            // attn flush: 16 rows x 32 cols; 128B contiguous per row.
            // (wave-private pbw; same-wave DS ops are in program order)
            #pragma unroll
            for (int r2 = 0; r2 < 2; ++r2) {
                const int row = r2 * 8 + (lane >> 3);
                short4v p4 = *reinterpret_cast<const short4v*>(&pbw[w][row][(lane & 7) * 4]);
                float4v o;
                o[0] = bf2f((unsigned short)p4[0]);
                o[1] = bf2f((unsigned short)p4[1]);
                o[2] = bf2f((unsigned short)p4[2]);
                o[3] = bf2f((unsigned short)p4[3]);
                *reinterpret_cast<float4v*>(
                    &attnb[(size_t)(qg + row) * S_LEN + c * CH + s2 * 32 + (lane & 7) * 4]) = o;
            }
            // PV: A = P-frag, B = V^T frags from swizzled vbuf
            short8v pa = *reinterpret_cast<const short8v*>(&pbw[w][lq][lg * 8]);
            #pragma unroll
            for (int dt = 0; dt < 4; ++dt) {
                const int d = dt * 16 + lq;
                short8v bv = *reinterpret_cast<const short8v*>(
                    &vbuf[d * 128 + (((s2 * 64 + lg * 16) ^ vswz) >> 1)]);
                cacc[dt] = __builtin_amdgcn_mfma_f32_16x16x32_bf16(pa, bv, cacc[dt], 0, 0, 0);
            }
        }
    }

    // ---- ctx: wave-owned rows, direct stores (cacc[dt][r] = ctx[q=lg*4+r][d=dt*16+lq])
    float* ctxb = ctx + base;
    #pragma unroll
    for (int dt = 0; dt < 4; ++dt)
        #pragma unroll
        for (int r = 0; r < 4; ++r)
            ctxb[(size_t)(qg + lg * 4 + r) * D_K + dt * 16 + lq] = cacc[dt][r];
}

// ---------------- fallback (no workspace): self-contained ----------------
__global__ __launch_bounds__(512)
void sdpa_fallback_kernel(const float* __restrict__ Qp, const float* __restrict__ Kp,
                          const float* __restrict__ Vp,
                          float* __restrict__ ctx, float* __restrict__ attn) {
    const int qt = blockIdx.x, bh = blockIdx.y, tid = threadIdx.x;
    const int w = tid >> 6, lane = tid & 63, lq = lane & 15, lg = lane >> 4;
    const int qg = qt * 16, kw = w * 256;
    const size_t base = (size_t)bh * S_LEN * D_K;
    __shared__ __align__(16) char smem_raw[8 * 16 * 136 * 2];
    __shared__ float red_s[16][8];
    auto pbuf = reinterpret_cast<unsigned short(*)[16][136]>(smem_raw);
    auto ctxp = reinterpret_cast<float(*)[16][64]>(smem_raw);

    short8v q0, q1;
    {
        const float* qr = Qp + base + (size_t)(qg + lq) * D_K + lg * 8;
        #pragma unroll
        for (int j = 0; j < 8; ++j) { q0[j] = (short)f2bf(qr[j]); q1[j] = (short)f2bf(qr[32 + j]); }
    }
    float4v acc[16];
    #pragma unroll
    for (int kt = 0; kt < 16; ++kt) acc[kt] = (float4v)0.0f;
    #pragma unroll
    for (int kt = 0; kt < 16; ++kt) {
        const float* kr = Kp + base + (size_t)(kw + kt * 16 + lq) * D_K + lg * 8;
        short8v k0, k1;
        #pragma unroll
        for (int j = 0; j < 8; ++j) { k0[j] = (short)f2bf(kr[j]); k1[j] = (short)f2bf(kr[32 + j]); }
        acc[kt] = __builtin_amdgcn_mfma_f32_16x16x32_bf16(k0, q0, acc[kt], 0, 0, 0);
        acc[kt] = __builtin_amdgcn_mfma_f32_16x16x32_bf16(k1, q1, acc[kt], 0, 0, 0);
    }
    float s = 0.f;
    #pragma unroll
    for (int kt = 0; kt < 16; ++kt)
        #pragma unroll
        for (int r = 0; r < 4; ++r) {
            float p = exp2f(acc[kt][r] * CEXP);
            acc[kt][r] = p; s += p;
        }
    s += __shfl_xor(s, 16, 64);
    s += __shfl_xor(s, 32, 64);
    if (lane < 16) red_s[lane][w] = s;
    __syncthreads();
    float gs = red_s[lq][0];
    #pragma unroll
    for (int ww = 1; ww < 8; ++ww) gs += red_s[lq][ww];
    const float rsv = 1.0f / gs;
    #pragma unroll
    for (int kt = 0; kt < 16; ++kt) acc[kt] = acc[kt] * rsv;

    float4v cacc[4];
    #pragma unroll
    for (int dt = 0; dt < 4; ++dt) cacc[dt] = (float4v)0.0f;
    #pragma unroll
    for (int half = 0; half < 2; ++half) {
        #pragma unroll
        for (int kth = 0; kth < 8; ++kth) {
            const int kt = half * 8 + kth;
            unsigned p01 = (unsigned)f2bf(acc[kt][0]) | ((unsigned)f2bf(acc[kt][1]) << 16);
            unsigned p23 = (unsigned)f2bf(acc[kt][2]) | ((unsigned)f2bf(acc[kt][3]) << 16);
            unsigned* dst = reinterpret_cast<unsigned*>(&pbuf[w][lq][kth * 16 + lg * 4]);
            dst[0] = p01; dst[1] = p23;
        }
        #pragma unroll
        for (int s2 = 0; s2 < 4; ++s2) {
            short8v pa = *reinterpret_cast<const short8v*>(&pbuf[w][lq][s2 * 32 + lg * 8]);
            const int kk = kw + half * 128 + s2 * 32 + lg * 8;
            #pragma unroll
            for (int dt = 0; dt < 4; ++dt) {
                short8v bv;
                #pragma unroll
                for (int j = 0; j < 8; ++j)
                    bv[j] = (short)f2bf(Vp[base + (size_t)(kk + j) * D_K + dt * 16 + lq]);
                cacc[dt] = __builtin_amdgcn_mfma_f32_16x16x32_bf16(pa, bv, cacc[dt], 0, 0, 0);
            }
        }
    }
    __syncthreads();
    #pragma unroll
    for (int dt = 0; dt < 4; ++dt)
        #pragma unroll
        for (int r = 0; r < 4; ++r)
            ctxp[w][lg * 4 + r][dt * 16 + lq] = cacc[dt][r];
    __syncthreads();
    float* ctxb = ctx + base;
    for (int idx = tid; idx < 16 * 64; idx += 512) {
        const int q = idx >> 6, d = idx & 63;
        float sum = 0.f;
        #pragma unroll
        for (int ww = 0; ww < 8; ++ww) sum += ctxp[ww][q][d];
        ctxb[(size_t)(qg + q) * D_K + d] = sum;
    }
    float* attnb = attn + (size_t)bh * S_LEN * S_LEN + (size_t)(qg + lq) * S_LEN + kw + lg * 4;
    #pragma unroll
    for (int kt = 0; kt < 16; ++kt)
        *reinterpret_cast<float4v*>(attnb + kt * 16) = acc[kt];
}

extern "C" void kernel_launch(void* const* d_in, const int* in_sizes, int n_in,
                              void* d_out, int out_size, void* d_ws, size_t ws_size,
                              hipStream_t stream) {
    const float* Q = (const float*)d_in[0];
    const float* K = (const float*)d_in[1];
    const float* V = (const float*)d_in[2];
    float* ctx  = (float*)d_out;
    float* attn = ctx + (size_t)NBH * S_LEN * D_K;

    const size_t nel  = (size_t)NBH * S_LEN * D_K;       // 6,291,456
    const size_t nvt  = (size_t)NBH * D_K * VT_STRIDE;
    const size_t need = (nel + nvt) * 2;

    if (ws_size >= need) {
        unsigned short* Kbf = (unsigned short*)d_ws;
        unsigned short* VT  = Kbf + nel;
        conv_k_kernel<<<2048, 256, 0, stream>>>(K, Kbf);
        trans_v_kernel<<<dim3(32, 48), 256, 0, stream>>>(V, VT);
        sdpa_fused_kernel<<<dim3(16, 48), 512, 0, stream>>>(Q, Kbf, VT, ctx, attn);
    } else {
        sdpa_fallback_kernel<<<dim3(128, 48), 512, 0, stream>>>(Q, K, V, ctx, attn);
    }
}